// Round 1
// baseline (55.369 us; speedup 1.0000x reference)
//
#include <hip/hip_runtime.h>

// ResonantHTT embedding, MI355X.
// out[n, D0*128 + d1*16 + d2*4 + d3] =
//   sum_{a,b,c} core0[i0,0,a,D0]*cos(phase[a]) * core1[i1,a,b,d1]
//             * core2[i2,b,c,d2] * core3[i3,c,0,d3]
// Kernel 1: per suffix s=(i1,i2,i3) in [0,4096):
//   F[b, q=(d2*4+d3)] = sum_c core2[i2][b,c,d2] * core3[i3][c,d3]   (4K MAC)
//   G[a, d1*16+q]     = sum_b core1[i1][a,b,d1] * F[b,q]            (32K MAC)
//   -> G table 4096 x 2048 f32 = 32 MB in d_ws
// Kernel 2: per token: out[D0*128+c] = sum_a A[i0][a,D0] * G[id&4095][a,c]

#define BSTR 132   // padded LDS row stride for core1 tile (16 floats/row of 128 +4)
#define CSTR 68    // padded LDS row stride for core2 tile (64 +4)

__global__ __launch_bounds__(256) void k_build_G(
    const float* __restrict__ core1, const float* __restrict__ core2,
    const float* __restrict__ core3, float* __restrict__ G)
{
  __shared__ float lds[4][16*BSTR + 16*CSTR + 64 + 256];
  const int wave = threadIdx.x >> 6;
  const int lane = threadIdx.x & 63;
  const int s  = blockIdx.x * 4 + wave;       // suffix
  const int i1 = s >> 8, i2 = (s >> 4) & 15, i3 = s & 15;

  float* Bl = lds[wave];                      // core1[i1], padded [a][b*8+d1]
  float* Cl = Bl + 16*BSTR;                   // core2[i2], padded [b][c*4+d2]
  float* El = Cl + 16*CSTR;                   // core3[i3]  [c*4+d3]
  float* Fl = El + 64;                        // F [b*16+q]

  const float* Bg = core1 + i1*2048;
  const float* Cg = core2 + i2*1024;
  const float* Eg = core3 + i3*64;

  // ---- stage core1 (2048 f32) into LDS, padded rows ----
  #pragma unroll
  for (int j = 0; j < 8; ++j) {
    int idx = (j*64 + lane) * 4;
    float4 v = *reinterpret_cast<const float4*>(Bg + idx);
    *reinterpret_cast<float4*>(Bl + (idx >> 7)*BSTR + (idx & 127)) = v;
  }
  // ---- stage core2 (1024 f32) ----
  #pragma unroll
  for (int j = 0; j < 4; ++j) {
    int idx = (j*64 + lane) * 4;
    float4 v = *reinterpret_cast<const float4*>(Cg + idx);
    *reinterpret_cast<float4*>(Cl + (idx >> 6)*CSTR + (idx & 63)) = v;
  }
  // ---- stage core3 (64 f32) ----
  if (lane < 16) {
    float4 v = *reinterpret_cast<const float4*>(Eg + lane*4);
    *reinterpret_cast<float4*>(El + lane*4) = v;
  }
  __syncthreads();

  // ---- step 1: F[b][q] = sum_c C[b][c][d2] * E[c][d3] ----
  {
    const int bg = lane >> 4, q = lane & 15;
    const int d2 = q >> 2, d3 = q & 3;
    #pragma unroll
    for (int i = 0; i < 4; ++i) {
      const int b = bg*4 + i;
      float acc = 0.f;
      #pragma unroll
      for (int c = 0; c < 16; ++c)
        acc += Cl[b*CSTR + c*4 + d2] * El[c*4 + d3];
      Fl[b*16 + q] = acc;
    }
  }
  __syncthreads();

  // ---- step 2: G[a][d1][q] = sum_b B[a][b*8+d1] * F[b][q] ----
  {
    const int ag = lane >> 4, q = lane & 15;
    float fcol[16];
    #pragma unroll
    for (int b = 0; b < 16; ++b) fcol[b] = Fl[b*16 + q];

    float acc[4][8];
    #pragma unroll
    for (int i = 0; i < 4; ++i)
      #pragma unroll
      for (int d = 0; d < 8; ++d) acc[i][d] = 0.f;

    #pragma unroll
    for (int i = 0; i < 4; ++i) {
      const int a = ag*4 + i;
      #pragma unroll
      for (int b = 0; b < 16; ++b) {
        float4 b0 = *reinterpret_cast<const float4*>(Bl + a*BSTR + b*8);
        float4 b1 = *reinterpret_cast<const float4*>(Bl + a*BSTR + b*8 + 4);
        const float f = fcol[b];
        acc[i][0] += b0.x*f; acc[i][1] += b0.y*f;
        acc[i][2] += b0.z*f; acc[i][3] += b0.w*f;
        acc[i][4] += b1.x*f; acc[i][5] += b1.y*f;
        acc[i][6] += b1.z*f; acc[i][7] += b1.w*f;
      }
    }

    float* Gs = G + (size_t)s * 2048;
    #pragma unroll
    for (int i = 0; i < 4; ++i) {
      const int a = ag*4 + i;
      #pragma unroll
      for (int d1 = 0; d1 < 8; ++d1)
        Gs[a*128 + d1*16 + q] = acc[i][d1];
    }
  }
}

__global__ __launch_bounds__(256) void k_out(
    const int* __restrict__ ids, const float* __restrict__ core0,
    const float* __restrict__ phase, const float* __restrict__ G,
    float* __restrict__ out)
{
  __shared__ float A[2048];   // core0 * cos(phase), [i0][a][D0]
  #pragma unroll
  for (int j = 0; j < 8; ++j) {
    const int idx = j*256 + threadIdx.x;
    A[idx] = core0[idx] * cosf(phase[(idx >> 3) & 15]);
  }
  __syncthreads();

  const int wave = threadIdx.x >> 6, lane = threadIdx.x & 63;
  const int n = blockIdx.x * 4 + wave;
  const int id = ids[n];
  const int i0 = id >> 12;
  const int suf = id & 4095;
  const float* __restrict__ Gp = G + (size_t)suf * 2048;
  const float* Ap = A + i0*128;

  float acc[16];
  #pragma unroll
  for (int k = 0; k < 16; ++k) acc[k] = 0.f;

  #pragma unroll
  for (int a = 0; a < 16; ++a) {
    float4 a0 = *reinterpret_cast<const float4*>(Ap + a*8);     // broadcast LDS
    float4 a1 = *reinterpret_cast<const float4*>(Ap + a*8 + 4);
    float g0 = Gp[a*128 + lane];        // coalesced 256B
    float g1 = Gp[a*128 + 64 + lane];
    acc[0] += a0.x*g0; acc[1] += a0.y*g0; acc[2] += a0.z*g0; acc[3] += a0.w*g0;
    acc[4] += a1.x*g0; acc[5] += a1.y*g0; acc[6] += a1.z*g0; acc[7] += a1.w*g0;
    acc[8]  += a0.x*g1; acc[9]  += a0.y*g1; acc[10] += a0.z*g1; acc[11] += a0.w*g1;
    acc[12] += a1.x*g1; acc[13] += a1.y*g1; acc[14] += a1.z*g1; acc[15] += a1.w*g1;
  }

  float* op = out + (size_t)n * 1024;
  #pragma unroll
  for (int d = 0; d < 8; ++d) {
    op[d*128 + lane]      = acc[d];
    op[d*128 + 64 + lane] = acc[8 + d];
  }
}

extern "C" void kernel_launch(void* const* d_in, const int* in_sizes, int n_in,
                              void* d_out, int out_size, void* d_ws, size_t ws_size,
                              hipStream_t stream) {
  const int*   ids   = (const int*)  d_in[0];
  const float* core0 = (const float*)d_in[1];
  const float* core1 = (const float*)d_in[2];
  const float* core2 = (const float*)d_in[3];
  const float* core3 = (const float*)d_in[4];
  const float* phase = (const float*)d_in[5];
  float* out = (float*)d_out;
  float* G   = (float*)d_ws;                 // needs 32 MB

  const int tokens = in_sizes[0];            // 16384
  hipLaunchKernelGGL(k_build_G, dim3(4096/4), dim3(256), 0, stream,
                     core1, core2, core3, G);
  hipLaunchKernelGGL(k_out, dim3(tokens/4), dim3(256), 0, stream,
                     ids, core0, phase, G, out);
}